// Round 10
// baseline (289.283 us; speedup 1.0000x reference)
//
#include <hip/hip_runtime.h>

#define ROW_LEN 128
#define NPAIR (129 * 129)   // (seq, uniq) pairs, each in [0,128]

typedef int v2i __attribute__((ext_vector_type(2)));

// Kernel A: precompute MLP(feats(seq,uniq)) for all 16641 pairs -> table[p][32].
__global__ __launch_bounds__(256) void mlp_table_kernel(
    const float* __restrict__ W1, const float* __restrict__ b1,
    const float* __restrict__ W2, const float* __restrict__ b2,
    float* __restrict__ table)
{
    const int tid = blockIdx.x * 256 + threadIdx.x;
    if (tid >= NPAIR * 32) return;
    const int p = tid >> 5;
    const int j = tid & 31;
    const int seq  = p / 129;
    const int uniq = p % 129;
    const float f0 = (float)seq  * (1.0f / 128.0f);
    const float f1 = (float)uniq * (1.0f / 128.0f);
    const float f2 = (seq > 0) ? ((float)uniq / (float)seq) : 0.0f;

    float acc = b2[j];
    #pragma unroll
    for (int jj = 0; jj < 32; ++jj) {
        float h = b1[jj];                 // lane-uniform -> scalar loads
        h = fmaf(f0, W1[jj],      h);
        h = fmaf(f1, W1[32 + jj], h);
        h = fmaf(f2, W1[64 + jj], h);
        h = fmaxf(h, 0.0f);
        acc = fmaf(h, W2[jj * 32 + j], acc);
    }
    table[tid] = fmaxf(acc, 0.0f);
}

// Kernel B: one row per wave. Hashed 1024-bit per-row set (32 LDS words,
// slot = tok & 1023) + exact ballot verify loop for candidates whose bit was
// already set (hash collision or duplicate; E~2/row). Zeroing = ONE
// ds_write_b32. NT loads/stores keep the zero-reuse streams out of L2
// (R9-proven). LDS 512 B/block -> occupancy wave-limited (~32 waves/CU).
// Exact for any data: heads hold distinct tokens (slot is a function of the
// token; first setter of a slot is its unique head); the loop adds each
// distinct candidate token once iff no head already represents it.
__global__ __launch_bounds__(256) void rows_kernel(
    const int* __restrict__ ids, const int* __restrict__ amask,
    const float* __restrict__ table, float* __restrict__ out, int B)
{
    __shared__ unsigned bm[4][32];     // 128 B hashed set per wave

    const int wave = threadIdx.x >> 6;
    const int lane = threadIdx.x & 63;
    const long row = (long)blockIdx.x * 4 + wave;
    if (row >= B) return;              // B % 4 == 0; cosmetic

    // NT coalesced loads: lane i covers row positions [2i, 2i+2)
    const long v = row * 64 + lane;
    const v2i id2 = __builtin_nontemporal_load((const v2i*)ids + v);
    const v2i mk2 = __builtin_nontemporal_load((const v2i*)amask + v);

    // zero own 32-word set: single ds_write_b32 from half the lanes
    unsigned* t = bm[wave];
    if (lane < 32) t[lane] = 0u;

    const bool mx = (mk2.x != 0);
    const bool my = (mk2.y != 0);
    const unsigned tx = (unsigned)id2.x;
    const unsigned ty = (unsigned)id2.y;

    int h0 = 0, h1 = 0;                // head flags (claimed a fresh bit)
    if (mx) {
        const unsigned m = 1u << (tx & 31u);
        h0 = ((atomicOr(&t[(tx >> 5) & 31u], m) & m) == 0u);
    }
    if (my) {
        const unsigned m = 1u << (ty & 31u);
        h1 = ((atomicOr(&t[(ty >> 5) & 31u], m) & m) == 0u);
    }

    const int seq = __popcll(__ballot(mx)) + __popcll(__ballot(my));
    int uniq = __popcll(__ballot(h0)) + __popcll(__ballot(h1));

    // candidates: masked, bit already set (dup or hash collision). E~2 iters.
    unsigned long long p0 = __ballot(mx && !h0);
    unsigned long long p1 = __ballot(my && !h1);
    while (p0 | p1) {
        int T;
        if (p0) T = __builtin_amdgcn_readlane(id2.x, __ffsll((long long)p0) - 1);
        else    T = __builtin_amdgcn_readlane(id2.y, __ffsll((long long)p1) - 1);
        const unsigned long long w =
            __ballot((h0 && id2.x == T) || (h1 && id2.y == T));
        uniq += (w == 0ull);           // distinct unrepresented token: count once
        p0 &= ~__ballot(id2.x == T);   // clear every instance of T
        p1 &= ~__ballot(id2.y == T);
    }

    // epilogue: 128B L2-hot table gather, contiguous NT 128B store
    const int p = seq * 129 + uniq;
    if (lane < 32) {
        const float r = table[p * 32 + lane];
        __builtin_nontemporal_store(r, out + row * 32 + lane);
    }
}

extern "C" void kernel_launch(void* const* d_in, const int* in_sizes, int n_in,
                              void* d_out, int out_size, void* d_ws, size_t ws_size,
                              hipStream_t stream) {
    const int*   ids   = (const int*)d_in[0];
    const int*   amask = (const int*)d_in[1];
    const float* W1    = (const float*)d_in[2];
    const float* b1    = (const float*)d_in[3];
    const float* W2    = (const float*)d_in[4];
    const float* b2    = (const float*)d_in[5];
    float* out   = (float*)d_out;
    float* table = (float*)d_ws;       // NPAIR*32*4 = 2.13 MB of ws

    const int B = in_sizes[0] / ROW_LEN;              // 262144

    const int tblThreads = NPAIR * 32;
    mlp_table_kernel<<<(tblThreads + 255) / 256, 256, 0, stream>>>(W1, b1, W2, b2, table);

    // 1 row per wave, 4 waves per block
    rows_kernel<<<(B + 3) / 4, 256, 0, stream>>>(ids, amask, table, out, B);
}